// Round 6
// baseline (271.200 us; speedup 1.0000x reference)
//
#include <hip/hip_runtime.h>

// predicted (S,B,H,W) f32, target (B,S,H,W) f32, output (S,B,H,W) f32.
#define SS 10
#define BB 8
#define HH 512
#define WW 512
#define PLANE (HH * WW)
// Sentinel for out-of-image candidates: |t - BIGV| always loses to any valid
// candidate. Finite, so no inf-inf NaN.
#define BIGV 3.0e38f

// Each wave owns one 8-row band of one (s,b) plane and walks it with a
// rolling 3-row register window: 10 pred-row fetches per 8 output rows
// (1.25x) instead of 3x, and all streams are sequential.
#define RB 8
#define NBANDS (HH / RB)             // 64 bands per plane
#define NWAVES (SS * BB * NBANDS)    // 5120 waves
#define NBLK (NWAVES / 4)            // 1280 blocks of 256

typedef float f32x4 __attribute__((ext_vector_type(4)));

__global__ __launch_bounds__(256, 4) void shiftpred_kernel(
    const float* __restrict__ pred,
    const float* __restrict__ targ,
    float* __restrict__ out)
{
    // XCD swizzle (1280 % 8 == 0, bijective): each XCD gets 160 consecutive
    // swz-blocks = 640 consecutive bands -> vertically adjacent bands (which
    // share boundary pred rows) resolve in the same L2.
    int bid = blockIdx.x;
    int swz = (bid & 7) * (NBLK / 8) + (bid >> 3);

    int wv   = swz * 4 + (int)(threadIdx.x >> 6);   // 0..5119
    int lane = (int)(threadIdx.x & 63);
    int band = wv & (NBANDS - 1);
    int sb   = wv >> 6;                             // plane s*8+b, 0..79
    int h0   = band * RB;
    int w0   = lane << 3;                           // lane owns w0..w0+7

    const float* pp = pred + (size_t)sb * PLANE + w0;
    const float* tp = targ + (size_t)((sb & 7) * SS + (sb >> 3)) * PLANE + w0;
    float*       op = out  + (size_t)sb * PLANE + w0;

    const bool e0  = (lane == 0);
    const bool e63 = (lane == 63);

    // Load one pred row (2x float4); wave-uniform validity -> sentinel row.
    auto ldp = [&](int hr, f32x4& q0, f32x4& q1, bool valid) {
        if (valid) {
            q0 = *reinterpret_cast<const f32x4*>(pp + (size_t)hr * WW);
            q1 = *reinterpret_cast<const f32x4*>(pp + (size_t)hr * WW + 4);
        } else { q0 = BIGV; q1 = BIGV; }
    };
    // target is single-use: non-temporal (no L3 allocation).
    auto ldt = [&](int hr, f32x4& q0, f32x4& q1) {
        q0 = __builtin_nontemporal_load(
                 reinterpret_cast<const f32x4*>(tp + (size_t)hr * WW));
        q1 = __builtin_nontemporal_load(
                 reinterpret_cast<const f32x4*>(tp + (size_t)hr * WW + 4));
    };

    auto docompute = [&](int h, f32x4 a0, f32x4 a1, f32x4 b0, f32x4 b1,
                         f32x4 c0, f32x4 c1, f32x4 t0, f32x4 t1) {
        // Strip v[row][0..9] = pred[h+row-1][w0-1 .. w0+8].
        float v[3][10];
        #pragma unroll
        for (int k = 0; k < 4; ++k) {
            v[0][1 + k] = a0[k]; v[0][5 + k] = a1[k];
            v[1][1 + k] = b0[k]; v[1][5 + k] = b1[k];
            v[2][1 + k] = c0[k]; v[2][5 + k] = c1[k];
        }
        // w-halos from neighbor lanes; lane 0/63 are true image edges.
        float la = __shfl_up(a1[3], 1), ra = __shfl_down(a0[0], 1);
        float lb = __shfl_up(b1[3], 1), rb = __shfl_down(b0[0], 1);
        float lc = __shfl_up(c1[3], 1), rc = __shfl_down(c0[0], 1);
        v[0][0] = e0 ? BIGV : la;  v[0][9] = e63 ? BIGV : ra;
        v[1][0] = e0 ? BIGV : lb;  v[1][9] = e63 ? BIGV : rb;
        v[2][0] = e0 ? BIGV : lc;  v[2][9] = e63 ? BIGV : rc;

        float tv[8] = {t0[0], t0[1], t0[2], t0[3], t1[0], t1[1], t1[2], t1[3]};
        float res[8];
        #pragma unroll
        for (int j = 0; j < 8; ++j) {
            float t = tv[j];
            // Shift 0: (0,0) always valid; then shifts 1..9 in reference
            // order. Strict < keeps the earliest index (= argmin).
            float bestc = v[1][j + 1];
            float bestl = fabsf(t - bestc);
            #pragma unroll
            for (int xi = 0; xi < 3; ++xi) {
                #pragma unroll
                for (int yi = 0; yi < 3; ++yi) {
                    float c = v[xi][j + yi];
                    float l = fabsf(t - c);
                    if (l < bestl) { bestl = l; bestc = c; }
                }
            }
            res[j] = bestc;
        }
        f32x4 o0 = {res[0], res[1], res[2], res[3]};
        f32x4 o1 = {res[4], res[5], res[6], res[7]};
        // Non-temporal store: no write-allocate, no L3 pollution.
        __builtin_nontemporal_store(o0, reinterpret_cast<f32x4*>(op + (size_t)h * WW));
        __builtin_nontemporal_store(o1, reinterpret_cast<f32x4*>(op + (size_t)h * WW + 4));
    };

    f32x4 a0, a1, b0, b1, c0, c1, t0, t1;   // rolling window rows h-1,h,h+1 + targ
    f32x4 n0, n1, u0, u1;                   // prefetch (next pred row, next targ)

    ldp(h0 - 1, a0, a1, h0 > 0);
    ldp(h0,     b0, b1, true);
    ldp(h0 + 1, c0, c1, true);
    ldt(h0,     t0, t1);

    #pragma unroll
    for (int i = 0; i < RB; ++i) {
        if (i < RB - 1) {                   // compile-time under full unroll
            ldp(h0 + i + 2, n0, n1, (h0 + i + 2) < HH);  // wave-uniform check
            ldt(h0 + i + 1, u0, u1);
        }
        docompute(h0 + i, a0, a1, b0, b1, c0, c1, t0, t1);
        if (i < RB - 1) {                   // rotate window (SSA under unroll)
            a0 = b0; a1 = b1; b0 = c0; b1 = c1;
            c0 = n0; c1 = n1; t0 = u0; t1 = u1;
        }
    }
}

extern "C" void kernel_launch(void* const* d_in, const int* in_sizes, int n_in,
                              void* d_out, int out_size, void* d_ws, size_t ws_size,
                              hipStream_t stream) {
    const float* pred = (const float*)d_in[0];
    const float* targ = (const float*)d_in[1];
    // d_in[2] (mask) unused: reference uses weights = ones.
    float* out = (float*)d_out;
    shiftpred_kernel<<<NBLK, 256, 0, stream>>>(pred, targ, out);
}

// Round 7
// 240.646 us; speedup vs baseline: 1.1270x; 1.1270x over previous
//
#include <hip/hip_runtime.h>

// predicted (S,B,H,W) f32, target (B,S,H,W) f32, output (S,B,H,W) f32.
#define SS 10
#define BB 8
#define HH 512
#define WW 512
#define NSB (SS * BB)          // 80 planes
#define PLANE (HH * WW)
// Sentinel for out-of-image candidates: |t - BIGV| always loses to any valid
// candidate. Finite, so no inf-inf NaN.
#define BIGV 3.0e38f

#define NBLK 20480             // 256 threads each; 1 thread = 1 output quad
#define CPX (NBLK / 8)         // 2560 blocks per XCD chunk

__device__ __forceinline__ void load_row(float dst[6], const float* __restrict__ rp,
                                         int wb, bool rv) {
    // rp = clamped in-bounds row start + wb. Halo ternaries don't dereference
    // OOB (compiler doesn't speculate global loads) — proven in R3/R6 runs.
    float4 c4 = *reinterpret_cast<const float4*>(rp);
    float lft = (wb > 0)      ? rp[-1] : BIGV;
    float rgt = (wb + 4 < WW) ? rp[4]  : BIGV;
    dst[0] = rv ? lft  : BIGV;
    dst[1] = rv ? c4.x : BIGV;
    dst[2] = rv ? c4.y : BIGV;
    dst[3] = rv ? c4.z : BIGV;
    dst[4] = rv ? c4.w : BIGV;
    dst[5] = rv ? rgt  : BIGV;
}

__global__ __launch_bounds__(256) void shiftpred_kernel(
    const float* __restrict__ pred,
    const float* __restrict__ targ,
    float* __restrict__ out)
{
    // XCD-chunked bijective swizzle: XCD k gets blocks [k*2560, (k+1)*2560) of
    // the swizzled ordering = 10 whole (s,b) planes -> vertical halo re-reads
    // stay in the local L2, and each XCD walks its planes most-recent-first.
    int bid = blockIdx.x;
    int swz = (bid & 7) * CPX + (bid >> 3);
    int gtid = swz * 256 + (int)threadIdx.x;

    int wq  = gtid & 127;              // w-quad within row
    int h   = (gtid >> 7) & 511;
    int sbr = gtid >> 16;              // 0..79 in processing order
    int sb  = (NSB - 1) - sbr;         // descending plane index: harvest the
                                       // restore-resident L3 tail before our
                                       // own traffic evicts it (LRU).
    int s = sb >> 3, b = sb & 7;
    int wb = wq << 2;

    const float* pplane = pred + (size_t)sb * PLANE;
    const float* tplane = targ + (size_t)(b * SS + s) * PLANE;

    // 3 pred rows (h-1, h, h+1) x 6 floats (wb-1 .. wb+4) in registers.
    float v[3][10 - 4];                // [3][6]
    bool rv0 = (h > 0);
    bool rv2 = (h < HH - 1);
    int  hm  = rv0 ? (h - 1) : h;      // clamped, stays in-buffer
    int  hp  = rv2 ? (h + 1) : h;
    load_row(v[0], pplane + (size_t)hm * WW + wb, wb, rv0);
    load_row(v[1], pplane + (size_t)h  * WW + wb, wb, true);
    load_row(v[2], pplane + (size_t)hp * WW + wb, wb, rv2);

    float4 t4 = *reinterpret_cast<const float4*>(tplane + (size_t)h * WW + wb);
    float tv[4] = {t4.x, t4.y, t4.z, t4.w};

    float res[4];
    #pragma unroll
    for (int j = 0; j < 4; ++j) {
        float t = tv[j];
        // Shift 0: (0,0), always valid — initializes best. Then shifts 1..9
        // in reference order; strict < keeps the earliest index (= argmin).
        float bestc = v[1][j + 1];
        float bestl = fabsf(t - bestc);
        #pragma unroll
        for (int xi = 0; xi < 3; ++xi) {
            #pragma unroll
            for (int yi = 0; yi < 3; ++yi) {
                float c = v[xi][j + yi];
                float l = fabsf(t - c);
                if (l < bestl) { bestl = l; bestc = c; }
            }
        }
        res[j] = bestc;
    }

    // Dense wave store: 64 lanes x 16B contiguous = 1024B full lines.
    float4 o4 = make_float4(res[0], res[1], res[2], res[3]);
    *reinterpret_cast<float4*>(out + (size_t)sb * PLANE + (size_t)h * WW + wb) = o4;
}

extern "C" void kernel_launch(void* const* d_in, const int* in_sizes, int n_in,
                              void* d_out, int out_size, void* d_ws, size_t ws_size,
                              hipStream_t stream) {
    const float* pred = (const float*)d_in[0];
    const float* targ = (const float*)d_in[1];
    // d_in[2] (mask) unused: reference uses weights = ones.
    float* out = (float*)d_out;
    shiftpred_kernel<<<NBLK, 256, 0, stream>>>(pred, targ, out);
}

// Round 14
// 239.660 us; speedup vs baseline: 1.1316x; 1.0041x over previous
//
#include <hip/hip_runtime.h>

// predicted (S,B,H,W) f32, target (B,S,H,W) f32, output (S,B,H,W) f32.
#define SS 10
#define BB 8
#define HH 512
#define WW 512
#define NSB (SS * BB)          // 80 planes
#define PLANE (HH * WW)
// Sentinel for out-of-image candidates: |t - BIGV| always loses to any valid
// candidate. Finite, so no inf-inf NaN.
#define BIGV 3.0e38f

#define NBLK 20480             // thread-per-quad: 80*512*128 threads
#define CPX (NBLK / 8)         // 2560 blocks per XCD chunk

typedef float f32x4 __attribute__((ext_vector_type(4)));

__global__ __launch_bounds__(256) void shiftpred_kernel(
    const float* __restrict__ pred,
    const float* __restrict__ targ,
    float* __restrict__ out)
{
    // XCD-chunked bijective swizzle (20480 % 8 == 0): each XCD owns 10 whole
    // planes; vertical halo re-reads resolve in its local L2.  [R7-proven]
    int bid = blockIdx.x;
    int swz = (bid & 7) * CPX + (bid >> 3);
    int gtid = swz * 256 + (int)threadIdx.x;

    int wq   = gtid & 127;             // quad within row; wave = w in [256k, 256k+256)
    int h    = (gtid >> 7) & 511;
    int sbr  = gtid >> 16;             // 0..79 in processing order
    int sb   = (NSB - 1) - sbr;        // descending: harvest restore-resident
                                       // L3 tail before eviction  [R7-proven]
    int w0   = wq << 2;
    int lane = (int)(threadIdx.x & 63);

    const float* pp = pred + (size_t)sb * PLANE;
    const float* tp = targ + (size_t)((sb & 7) * SS + (sb >> 3)) * PLANE;

    const bool rvm = (h > 0);
    const bool rvp = (h < HH - 1);
    const int  hm  = rvm ? (h - 1) : h;   // clamped: address always in-buffer
    const int  hp  = rvp ? (h + 1) : h;

    // Dense row loads: each is 64 lanes x 16B = 1024B contiguous per wave.
    f32x4 qa, qb, qc;
    if (rvm) qa = *reinterpret_cast<const f32x4*>(pp + (size_t)hm * WW + w0);
    else     qa = BIGV;                // implicit splat  [R6-proven]
    qb = *reinterpret_cast<const f32x4*>(pp + (size_t)h * WW + w0);
    if (rvp) qc = *reinterpret_cast<const f32x4*>(pp + (size_t)hp * WW + w0);
    else     qc = BIGV;
    f32x4 t4 = *reinterpret_cast<const f32x4*>(tp + (size_t)h * WW + w0);

    // Halos: within-wave via shfl (lane-1's [3] / lane+1's [0])  [R6-proven];
    // at wave seams (lane 0/63, w=256k boundary) a 1-lane predicated scalar
    // load  [R7-proven construct]; true image edges -> BIGV.
    const bool e0  = (lane == 0);
    const bool e63 = (lane == 63);
    const bool seamL = e0  && (w0 > 0);        // left neighbor exists but is
                                               // outside this wave
    const bool seamR = e63 && (w0 + 4 < WW);

    float la, ra, lb, rb, lc, rc;
    {
        // row a (h-1)
        float su = __shfl_up(qa[3], 1);
        float sd = __shfl_down(qa[0], 1);
        const float* rowp = pp + (size_t)hm * WW + w0;
        float lv = (seamL && rvm) ? rowp[-1] : BIGV;
        float rv = (seamR && rvm) ? rowp[4]  : BIGV;
        la = e0 ? lv : su;
        ra = e63 ? rv : sd;
    }
    {
        // row b (h), always valid
        float su = __shfl_up(qb[3], 1);
        float sd = __shfl_down(qb[0], 1);
        const float* rowp = pp + (size_t)h * WW + w0;
        float lv = seamL ? rowp[-1] : BIGV;
        float rv = seamR ? rowp[4]  : BIGV;
        lb = e0 ? lv : su;
        rb = e63 ? rv : sd;
    }
    {
        // row c (h+1)
        float su = __shfl_up(qc[3], 1);
        float sd = __shfl_down(qc[0], 1);
        const float* rowp = pp + (size_t)hp * WW + w0;
        float lv = (seamL && rvp) ? rowp[-1] : BIGV;
        float rv = (seamR && rvp) ? rowp[4]  : BIGV;
        lc = e0 ? lv : su;
        rc = e63 ? rv : sd;
    }

    // v[row][0..5] = pred[h+row-1][w0-1 .. w0+4].
    float v[3][6];
    v[0][0] = la; v[1][0] = lb; v[2][0] = lc;
    v[0][5] = ra; v[1][5] = rb; v[2][5] = rc;
    #pragma unroll
    for (int k = 0; k < 4; ++k) {
        v[0][1 + k] = qa[k]; v[1][1 + k] = qb[k]; v[2][1 + k] = qc[k];
    }

    f32x4 res;
    #pragma unroll
    for (int j = 0; j < 4; ++j) {
        float t = t4[j];
        // Shift 0: (0,0), always valid — initializes best. Then shifts 1..9
        // in reference order; strict < keeps the earliest index (= argmin).
        float bestc = v[1][j + 1];
        float bestl = fabsf(t - bestc);
        #pragma unroll
        for (int xi = 0; xi < 3; ++xi) {
            #pragma unroll
            for (int yi = 0; yi < 3; ++yi) {
                float c = v[xi][j + yi];
                float l = fabsf(t - c);
                if (l < bestl) { bestl = l; bestc = c; }
            }
        }
        res[j] = bestc;
    }

    // Dense 1024B wave store.
    *reinterpret_cast<f32x4*>(out + (size_t)sb * PLANE + (size_t)h * WW + w0) = res;
}

extern "C" void kernel_launch(void* const* d_in, const int* in_sizes, int n_in,
                              void* d_out, int out_size, void* d_ws, size_t ws_size,
                              hipStream_t stream) {
    const float* pred = (const float*)d_in[0];
    const float* targ = (const float*)d_in[1];
    // d_in[2] (mask) unused: reference uses weights = ones.
    float* out = (float*)d_out;
    shiftpred_kernel<<<NBLK, 256, 0, stream>>>(pred, targ, out);
}